// Round 11
// baseline (413.279 us; speedup 1.0000x reference)
//
#include <hip/hip_runtime.h>

// MPLayer: out[i,m] = (1/K) sum_{j,l,n} edges[i,j,n] * nodes[nlist[i,j],l] * w[l,m,n]
// N=50000, K=32, F=128, E=16. Two-phase MFMA (fp16 in, fp32 acc):
//   phase 1: T[i][c'] (permuted c-order), per 16-wide l-tile one 16x16x32 MFMA
//   phase 2: out = T @ W2t^T / K, with W2t columns stored in the SAME permuted order
// v10 = v9 (verified, 191us k_mp) with the OCCUPANCY lever: RPB 32->16.
//   r10 post-mortem: v9's WRITE 59.4MB (not the predicted 25.6) + FETCH +26MB =
//   ~30MB scratch spill (unified VGPR+AGPR file hit the (256,4) 128-reg cap:
//   64 VGPR + 64 acc-AGPR). And LDS 40960x4 = exactly 160KiB -> only 3 blocks/CU
//   fit (occ 36%). All pipes <8% -> concurrency-starved.
//   - RPB=16: s_T = 16x512 halves (16KB), s_G unchanged (8KB) -> 24KB LDS
//     -> 6 blocks/CU (144KB, 16KB slack), 24 waves/CU, launch_bounds(256,6).
//   - acc halves to 2 float4v (8 regs), fe/nb halve -> ~70 total regs < 85 cap
//     -> no spill (watch WRITE_SIZE ~26MB as the no-spill witness).
//   - depth-2 scalar prefetch kept (pA even r, pB odd r; cross-chunk r0+r1).
//   - phase 2: single T-row read (c16), 2 MFMAs/kt; epilogue stages 16x128
//     floats in dead s_T -> one contiguous 8KB block write.
//   50000 = 16*3125 exactly -> no tail block.

typedef _Float16 half8  __attribute__((ext_vector_type(8)));
typedef _Float16 half4v __attribute__((ext_vector_type(4)));
typedef float    float4v __attribute__((ext_vector_type(4)));
typedef int      int4v  __attribute__((ext_vector_type(4)));
typedef unsigned int uint;

#define NF 128
#define NK 32
#define NE 16
#define RPB 16

__global__ __launch_bounds__(256) void k_prep_nodes(const float* __restrict__ src,
                                                    _Float16* __restrict__ dst, int n4) {
    int i = blockIdx.x * 256 + threadIdx.x;
    if (i < n4) {
        float4v v = ((const float4v*)src)[i];
        half4v h;
        h[0] = (_Float16)v[0]; h[1] = (_Float16)v[1];
        h[2] = (_Float16)v[2]; h[3] = (_Float16)v[3];
        ((half4v*)dst)[i] = h;
    }
}

// W2t permuted: storage index o = m*2048 + ch*512 + ltq*64 + n*4 + g
// corresponds to w[l, m, n] with l = ch*32 + (ltq>>2)*16 + (ltq&3)*4 + g.
__global__ __launch_bounds__(256) void k_prep_w(const float* __restrict__ w,
                                                _Float16* __restrict__ w2t) {
    int o  = blockIdx.x * 256 + threadIdx.x;   // 262144 total, exact grid
    int m  = o >> 11;
    int cf = o & 2047;
    int ch = cf >> 9;
    int cp = cf & 511;
    int ltq = cp >> 6;
    int n   = (cp >> 2) & 15;
    int g   = cp & 3;
    int l = ch * 32 + (ltq >> 2) * 16 + (ltq & 3) * 4 + g;
    w2t[o] = (_Float16)w[(l * NF + m) * NE + n];
}

// MFMA 16x16x32 f16 layouts (verified v1/v2/v6/v9):
//   A: lane holds A[m = lane&15][k = (lane>>4)*8 + jj]
//   B: lane holds B[k = (lane>>4)*8 + jj][n = lane&15]
//   C/D: lane holds D[row = (lane>>4)*4 + g][col = lane&15]
__global__ __launch_bounds__(256, 6) void k_mp(const _Float16* __restrict__ nodes_h,
                                               const int* __restrict__ nlist,
                                               const float* __restrict__ edges,
                                               const _Float16* __restrict__ w2t,
                                               float* __restrict__ out, int N) {
    // s_T: 16 i-rows x 512 permuted-c halves per chunk, XOR-swizzled (16KB).
    // s_G: per-wave gather staging, 32 j-rows x 32 cols, block-XOR by j>>3 (8KB).
    __shared__ __align__(16) _Float16 s_T[RPB * 512];
    __shared__ __align__(16) _Float16 s_G[4 * NK * 32];

    const int tid  = threadIdx.x;
    const int wv   = tid >> 6;
    const int ln   = tid & 63;
    const int quad = ln >> 4;
    const int c16  = ln & 15;
    const int row0 = blockIdx.x * RPB;

    _Float16* __restrict__ gbuf = &s_G[wv * (NK * 32)];
    const float4v zf = {0.f, 0.f, 0.f, 0.f};

    // ---- edge B-fragments (4 i-rows per wave, persistent across chunks) ----
    half8 fe[4];
    #pragma unroll
    for (int r = 0; r < 4; ++r) {
        int rg = row0 + wv * 4 + r; if (rg > N - 1) rg = N - 1;
        const float* ep = edges + (size_t)rg * (NK * NE) + quad * (8 * NE) + c16;
        #pragma unroll
        for (int jj = 0; jj < 8; ++jj) fe[r][jj] = (_Float16)ep[jj * NE];
    }

    // ---- neighbor row byte-offsets: lane stages rows j=jlane and jlane+16 ----
    const int jlane = ln >> 2;       // 0..15
    const int sub   = ln & 3;        // which 16B piece of the 64B chunk-row
    int nb0[4], nb1[4];
    #pragma unroll
    for (int r = 0; r < 4; ++r) {
        int rg = row0 + wv * 4 + r; if (rg > N - 1) rg = N - 1;
        nb0[r] = nlist[rg * NK + jlane]      << 8;   // *256 bytes per fp16 node row
        nb1[r] = nlist[rg * NK + 16 + jlane] << 8;
    }
    // staging write blocks, XOR by (j>>3)&3 (matches read side where j>>3 == quad)
    const int wblk0 = (sub ^ ((jlane >> 3) & 3)) << 3;
    const int wblk1 = (sub ^ (((jlane + 16) >> 3) & 3)) << 3;

    float4v a00 = zf, a01 = zf;
    const char* nbase = (const char*)nodes_h;

    // ---- depth-2 scalar prefetch: pA = pair for even r, pB = pair for odd r ----
    half8 pA0 = *(const half8*)(nbase + nb0[0] + sub * 16);
    half8 pA1 = *(const half8*)(nbase + nb1[0] + sub * 16);
    half8 pB0 = *(const half8*)(nbase + nb0[1] + sub * 16);
    half8 pB1 = *(const half8*)(nbase + nb1[1] + sub * 16);

    for (int ch = 0; ch < 4; ++ch) {
        // ================= phase 1 =================
        #pragma unroll
        for (int r = 0; r < 4; ++r) {
            const int il = wv * 4 + r;
            // consume this r's pair via the staging write (vmcnt wait lands here,
            // for a load issued 2 iterations ago), then reissue the freed slot.
            if ((r & 1) == 0) {
                *(half8*)&gbuf[jlane * 32 + wblk0]        = pA0;
                *(half8*)&gbuf[(jlane + 16) * 32 + wblk1] = pA1;
                if (r < 2) {
                    pA0 = *(const half8*)(nbase + nb0[r + 2] + ch * 64 + sub * 16);
                    pA1 = *(const half8*)(nbase + nb1[r + 2] + ch * 64 + sub * 16);
                }
            } else {
                *(half8*)&gbuf[jlane * 32 + wblk0]        = pB0;
                *(half8*)&gbuf[(jlane + 16) * 32 + wblk1] = pB1;
                if (r < 2) {
                    pB0 = *(const half8*)(nbase + nb0[r + 2] + ch * 64 + sub * 16);
                    pB1 = *(const half8*)(nbase + nb1[r + 2] + ch * 64 + sub * 16);
                }
            }
            // per-wave buffer: LDS ops from one wave complete in order; no barrier
            #pragma unroll
            for (int lt = 0; lt < 2; ++lt) {
                const int col   = lt * 16 + c16;
                const int rbase = quad * (8 * 32) + (col ^ (quad << 3));
                uint t0 = *(const unsigned short*)&gbuf[rbase + 0 * 32];
                uint t1 = *(const unsigned short*)&gbuf[rbase + 1 * 32];
                uint t2 = *(const unsigned short*)&gbuf[rbase + 2 * 32];
                uint t3 = *(const unsigned short*)&gbuf[rbase + 3 * 32];
                uint t4 = *(const unsigned short*)&gbuf[rbase + 4 * 32];
                uint t5 = *(const unsigned short*)&gbuf[rbase + 5 * 32];
                uint t6 = *(const unsigned short*)&gbuf[rbase + 6 * 32];
                uint t7 = *(const unsigned short*)&gbuf[rbase + 7 * 32];
                int4v pv;
                pv[0] = (int)(t0 | (t1 << 16));
                pv[1] = (int)(t2 | (t3 << 16));
                pv[2] = (int)(t4 | (t5 << 16));
                pv[3] = (int)(t6 | (t7 << 16));
                half8 av = __builtin_bit_cast(half8, pv);
                float4v d = __builtin_amdgcn_mfma_f32_16x16x32_f16(av, fe[r], zf, 0, 0, 0);
                // T store, permuted: c' = ltq*64 + c16*4 + g  (g contiguous -> b64)
                const int ltq  = lt * 4 + quad;
                const int cb   = ltq * 64 + c16 * 4;
                const int phys = cb ^ ((((ltq ^ il) & 7)) << 3);
                half4v hv;
                hv[0] = (_Float16)d[0]; hv[1] = (_Float16)d[1];
                hv[2] = (_Float16)d[2]; hv[3] = (_Float16)d[3];
                *(half4v*)&s_T[il * 512 + phys] = hv;
            }
        }
        __syncthreads();

        // ---- prefetch next chunk's r=0 and r=1 pairs (4 loads); they ride
        //      over phase 2's 32 MFMAs and land before next phase-1 starts ----
        if (ch < 3) {
            pA0 = *(const half8*)(nbase + nb0[0] + (ch + 1) * 64 + sub * 16);
            pA1 = *(const half8*)(nbase + nb1[0] + (ch + 1) * 64 + sub * 16);
            pB0 = *(const half8*)(nbase + nb0[1] + (ch + 1) * 64 + sub * 16);
            pB1 = *(const half8*)(nbase + nb1[1] + (ch + 1) * 64 + sub * 16);
        }

        // ================= phase 2 =================
        const _Float16* wr0 = w2t + ((size_t)(wv * 2 + 0) * 16 + c16) * 2048 + ch * 512;
        const _Float16* wr1 = w2t + ((size_t)(wv * 2 + 1) * 16 + c16) * 2048 + ch * 512;
        #pragma unroll 4
        for (int kt = 0; kt < 16; ++kt) {
            const int cb2  = kt * 32 + quad * 8;
            const int mask = (((cb2 >> 6) ^ c16) & 7) << 3;
            half8 t0 = *(const half8*)&s_T[c16 * 512 + (cb2 ^ mask)];
            half8 b0 = *(const half8*)(wr0 + cb2);
            half8 b1 = *(const half8*)(wr1 + cb2);
            a00 = __builtin_amdgcn_mfma_f32_16x16x32_f16(t0, b0, a00, 0, 0, 0);
            a01 = __builtin_amdgcn_mfma_f32_16x16x32_f16(t0, b1, a01, 0, 0, 0);
        }
        __syncthreads();   // before next chunk's phase 1 overwrites s_T
    }

    // ---- epilogue: stage through s_T (dead) -> one contiguous 8KB block write ----
    float* sf = (float*)s_T;
    const float sc = 1.0f / (float)NK;
    const int mb = (wv << 5) + c16;
    #pragma unroll
    for (int g = 0; g < 4; ++g) {
        const int r0 = quad * 4 + g;
        sf[r0 * NF + mb]      = a00[g] * sc;
        sf[r0 * NF + mb + 16] = a01[g] * sc;
    }
    __syncthreads();
    float* ob = out + (size_t)row0 * NF;          // 50000 = 16*3125: no tail
    #pragma unroll
    for (int u = 0; u < 2; ++u) {
        const int idx = (tid + u * 256) * 4;
        *(float4v*)&ob[idx] = *(const float4v*)&sf[idx];
    }
}

extern "C" void kernel_launch(void* const* d_in, const int* in_sizes, int n_in,
                              void* d_out, int out_size, void* d_ws, size_t ws_size,
                              hipStream_t stream) {
    const float* nodes = (const float*)d_in[0];
    const int*   nlist = (const int*)d_in[1];
    const float* edges = (const float*)d_in[2];
    const float* w     = (const float*)d_in[3];
    float* out = (float*)d_out;

    const int N = in_sizes[0] / NF;   // 50000

    _Float16* w2t     = (_Float16*)d_ws;                       // 512KB
    _Float16* nodes_h = (_Float16*)((char*)d_ws + 524288);     // 12.8MB

    const int n4 = (N * NF) / 4;
    k_prep_nodes<<<(n4 + 255) / 256, 256, 0, stream>>>(nodes, nodes_h, n4);
    k_prep_w<<<(NF * NF * NE) / 256, 256, 0, stream>>>(w, w2t);

    const int blocks = (N + RPB - 1) / RPB;                    // 3125
    k_mp<<<blocks, 256, 0, stream>>>(nodes_h, nlist, edges, w2t, out, N);
}

// Round 13
// 395.777 us; speedup vs baseline: 1.0442x; 1.0442x over previous
//
#include <hip/hip_runtime.h>

// MPLayer: out[i,m] = (1/K) sum_{j,l,n} edges[i,j,n] * nodes[nlist[i,j],l] * w[l,m,n]
// N=50000, K=32, F=128, E=16. Two-phase MFMA (fp16 in, fp32 acc):
//   phase 1: T[i][c'] (permuted c-order), per 16-wide l-tile one 16x16x32 MFMA
//   phase 2: out = T @ W2t^T / K, with W2t columns stored in the SAME permuted order
// v11 (resubmit after broker timeout; full re-audit passed) = v9 (verified 191us)
//   + 128B-granule gather, pipeline intact.
//   r11 post-mortem: occupancy 36->60% made it WORSE (281us) -> the limiter is
//   per-CU in-flight miss capacity (~64 slots: 2.11TB/s = 8.2GB/s/CU = 64x64B @
//   ~500ns). Depth (v7) and occupancy (v10) can't pass a slot cap; only more
//   BYTES PER SLOT can: 128B tx. v8's 128B attempt broke the pipeline; v11
//   keeps v9's structure: gather a full 128B line ONCE per chunk-PAIR (g=ch/2)
//   into s_G[32][64]; chunk 2g consumes pieces 0-3 via the verified transpose
//   path; chunk 2g+1's MFMAs run in the SAME r-iter (pieces 4-7) with outputs
//   held in 32 static VGPRs (hC1[8][2], fully unrolled - rule 20), written to
//   s_T during the odd chunk's loadless phase 1.
//   s_G mapping = strict 8-piece generalization of v9's verified 4-block XOR:
//     store: row j (=q*8+jl8), piece p8 -> half off j*64 + ((p8^q)<<3)
//     read:  piece = c*4+lt*2+(c16>>3), addr = (quad*8+jj)*64+((piece^quad)<<3)+(c16&7)
//     (v9 was the c=0, 32-half-row special case of this formula.)
//   s_T / phase-2 / w2t prep / staged epilogue byte-identical to v9.
//   LDS 32+16=48KB -> 3 blocks/CU; __launch_bounds__(256,3) (cap 170, est ~155,
//   avoids v9's (256,4)-forced spill -> WRITE should drop 59->26MB).

typedef _Float16 half8  __attribute__((ext_vector_type(8)));
typedef _Float16 half4v __attribute__((ext_vector_type(4)));
typedef float    float4v __attribute__((ext_vector_type(4)));
typedef int      int4v  __attribute__((ext_vector_type(4)));
typedef unsigned int uint;

#define NF 128
#define NK 32
#define NE 16
#define RPB 32

__global__ __launch_bounds__(256) void k_prep_nodes(const float* __restrict__ src,
                                                    _Float16* __restrict__ dst, int n4) {
    int i = blockIdx.x * 256 + threadIdx.x;
    if (i < n4) {
        float4v v = ((const float4v*)src)[i];
        half4v h;
        h[0] = (_Float16)v[0]; h[1] = (_Float16)v[1];
        h[2] = (_Float16)v[2]; h[3] = (_Float16)v[3];
        ((half4v*)dst)[i] = h;
    }
}

// W2t permuted: storage index o = m*2048 + ch*512 + ltq*64 + n*4 + g
// corresponds to w[l, m, n] with l = ch*32 + (ltq>>2)*16 + (ltq&3)*4 + g.
__global__ __launch_bounds__(256) void k_prep_w(const float* __restrict__ w,
                                                _Float16* __restrict__ w2t) {
    int o  = blockIdx.x * 256 + threadIdx.x;   // 262144 total, exact grid
    int m  = o >> 11;
    int cf = o & 2047;
    int ch = cf >> 9;
    int cp = cf & 511;
    int ltq = cp >> 6;
    int n   = (cp >> 2) & 15;
    int g   = cp & 3;
    int l = ch * 32 + (ltq >> 2) * 16 + (ltq & 3) * 4 + g;
    w2t[o] = (_Float16)w[(l * NF + m) * NE + n];
}

// MFMA 16x16x32 f16 layouts (verified v1/v2/v6/v9):
//   A: lane holds A[m = lane&15][k = (lane>>4)*8 + jj]
//   B: lane holds B[k = (lane>>4)*8 + jj][n = lane&15]
//   C/D: lane holds D[row = (lane>>4)*4 + g][col = lane&15]
__global__ __launch_bounds__(256, 3) void k_mp(const _Float16* __restrict__ nodes_h,
                                               const int* __restrict__ nlist,
                                               const float* __restrict__ edges,
                                               const _Float16* __restrict__ w2t,
                                               float* __restrict__ out, int N) {
    // s_T: 32 i-rows x 512 permuted-c halves per chunk, XOR-swizzled (32KB).
    // s_G: per-wave gather staging, 32 j-rows x 64 halves (full 128B line,
    //      covers a chunk PAIR), 8-piece XOR layout (16KB).
    __shared__ __align__(16) _Float16 s_T[RPB * 512];
    __shared__ __align__(16) _Float16 s_G[4 * NK * 64];

    const int tid  = threadIdx.x;
    const int wv   = tid >> 6;
    const int ln   = tid & 63;
    const int quad = ln >> 4;
    const int c16  = ln & 15;
    const int row0 = blockIdx.x * RPB;

    _Float16* __restrict__ gbuf = &s_G[wv * (NK * 64)];
    const float4v zf = {0.f, 0.f, 0.f, 0.f};

    // ---- edge B-fragments (persistent across chunks) ----
    half8 fe[8];
    #pragma unroll
    for (int r = 0; r < 8; ++r) {
        int rg = row0 + wv * 8 + r; if (rg > N - 1) rg = N - 1;
        const float* ep = edges + (size_t)rg * (NK * NE) + quad * (8 * NE) + c16;
        #pragma unroll
        for (int jj = 0; jj < 8; ++jj) fe[r][jj] = (_Float16)ep[jj * NE];
    }

    // ---- gather lanes: jl8 = ln>>3 (row within octet), p8 = ln&7 (16B piece);
    //      load q covers row q*8+jl8 -> one wave instr = 8 rows x 128B full lines
    const int jl8 = ln >> 3;
    const int p8  = ln & 7;
    int nb0[8], nb1[8], nb2[8], nb3[8];
    #pragma unroll
    for (int r = 0; r < 8; ++r) {
        int rg = row0 + wv * 8 + r; if (rg > N - 1) rg = N - 1;
        const int* np = nlist + rg * NK + jl8;
        nb0[r] = np[0]  << 8;        // *256 bytes per fp16 node row
        nb1[r] = np[8]  << 8;
        nb2[r] = np[16] << 8;
        nb3[r] = np[24] << 8;
    }
    const char* nbase = (const char*)nodes_h + (p8 << 4);

    // staging dest offsets (halves): row q*8+jl8, physical piece-slot p8^q
    const int wo0 = (0 * 8 + jl8) * 64 + ((p8 ^ 0) << 3);
    const int wo1 = (1 * 8 + jl8) * 64 + ((p8 ^ 1) << 3);
    const int wo2 = (2 * 8 + jl8) * 64 + ((p8 ^ 2) << 3);
    const int wo3 = (3 * 8 + jl8) * 64 + ((p8 ^ 3) << 3);

    float4v a00 = zf, a01 = zf, a10 = zf, a11 = zf;
    half4v  hC1[8][2];               // odd-chunk T contributions (static idx only)

    // ---- depth-2 prefetch: pA = even r set, pB = odd r set (4 x half8 each) ----
    half8 pA0 = *(const half8*)(nbase + nb0[0]);
    half8 pA1 = *(const half8*)(nbase + nb1[0]);
    half8 pA2 = *(const half8*)(nbase + nb2[0]);
    half8 pA3 = *(const half8*)(nbase + nb3[0]);
    half8 pB0 = *(const half8*)(nbase + nb0[1]);
    half8 pB1 = *(const half8*)(nbase + nb1[1]);
    half8 pB2 = *(const half8*)(nbase + nb2[1]);
    half8 pB3 = *(const half8*)(nbase + nb3[1]);

    for (int ch = 0; ch < 4; ++ch) {
        if ((ch & 1) == 0) {
            // ============ even chunk: gather pair-line + MFMA both halves ============
            const int chb = (ch >> 1) << 7;       // 128B per gather pair
            #pragma unroll
            for (int r = 0; r < 8; ++r) {
                const int il = wv * 8 + r;
                // consume this r's 4-line set; refill the slot for r+2
                if ((r & 1) == 0) {
                    *(half8*)&gbuf[wo0] = pA0;  *(half8*)&gbuf[wo1] = pA1;
                    *(half8*)&gbuf[wo2] = pA2;  *(half8*)&gbuf[wo3] = pA3;
                    if (r < 6) {
                        pA0 = *(const half8*)(nbase + nb0[r + 2] + chb);
                        pA1 = *(const half8*)(nbase + nb1[r + 2] + chb);
                        pA2 = *(const half8*)(nbase + nb2[r + 2] + chb);
                        pA3 = *(const half8*)(nbase + nb3[r + 2] + chb);
                    }
                } else {
                    *(half8*)&gbuf[wo0] = pB0;  *(half8*)&gbuf[wo1] = pB1;
                    *(half8*)&gbuf[wo2] = pB2;  *(half8*)&gbuf[wo3] = pB3;
                    if (r < 6) {
                        pB0 = *(const half8*)(nbase + nb0[r + 2] + chb);
                        pB1 = *(const half8*)(nbase + nb1[r + 2] + chb);
                        pB2 = *(const half8*)(nbase + nb2[r + 2] + chb);
                        pB3 = *(const half8*)(nbase + nb3[r + 2] + chb);
                    }
                }
                // per-wave buffer, in-order LDS: no barrier needed.
                // c = 0 (this chunk) and c = 1 (next chunk, held in regs)
                #pragma unroll
                for (int c = 0; c < 2; ++c) {
                    #pragma unroll
                    for (int lt = 0; lt < 2; ++lt) {
                        const int piece = c * 4 + lt * 2 + (c16 >> 3);
                        const int rbase = quad * 512 + ((piece ^ quad) << 3) + (c16 & 7);
                        uint t0 = *(const unsigned short*)&gbuf[rbase + 0 * 64];
                        uint t1 = *(const unsigned short*)&gbuf[rbase + 1 * 64];
                        uint t2 = *(const unsigned short*)&gbuf[rbase + 2 * 64];
                        uint t3 = *(const unsigned short*)&gbuf[rbase + 3 * 64];
                        uint t4 = *(const unsigned short*)&gbuf[rbase + 4 * 64];
                        uint t5 = *(const unsigned short*)&gbuf[rbase + 5 * 64];
                        uint t6 = *(const unsigned short*)&gbuf[rbase + 6 * 64];
                        uint t7 = *(const unsigned short*)&gbuf[rbase + 7 * 64];
                        int4v pv;
                        pv[0] = (int)(t0 | (t1 << 16));
                        pv[1] = (int)(t2 | (t3 << 16));
                        pv[2] = (int)(t4 | (t5 << 16));
                        pv[3] = (int)(t6 | (t7 << 16));
                        half8 av = __builtin_bit_cast(half8, pv);
                        float4v d = __builtin_amdgcn_mfma_f32_16x16x32_f16(av, fe[r], zf, 0, 0, 0);
                        half4v hv;
                        hv[0] = (_Float16)d[0]; hv[1] = (_Float16)d[1];
                        hv[2] = (_Float16)d[2]; hv[3] = (_Float16)d[3];
                        if (c == 0) {
                            // T store: c' = ltq*64 + c16*4 + g, XOR-swizzled by i-row
                            const int ltq  = lt * 4 + quad;
                            const int cb   = ltq * 64 + c16 * 4;
                            const int phys = cb ^ (((ltq ^ il) & 7) << 3);
                            *(half4v*)&s_T[il * 512 + phys] = hv;
                        } else {
                            hC1[r][lt] = hv;             // held for chunk ch+1
                        }
                    }
                }
            }
        } else {
            // ============ odd chunk: loadless phase 1 — dump held regs ============
            #pragma unroll
            for (int r = 0; r < 8; ++r) {
                const int il = wv * 8 + r;
                #pragma unroll
                for (int lt = 0; lt < 2; ++lt) {
                    const int ltq  = lt * 4 + quad;
                    const int cb   = ltq * 64 + c16 * 4;
                    const int phys = cb ^ (((ltq ^ il) & 7) << 3);
                    *(half4v*)&s_T[il * 512 + phys] = hC1[r][lt];
                }
            }
        }
        __syncthreads();

        // ---- at ch==1: prefetch gather-pair g=1's r=0,r=1 sets (8 loads);
        //      they ride over ch1's phase 2 + barrier, land for ch2 ----
        if (ch == 1) {
            pA0 = *(const half8*)(nbase + nb0[0] + 128);
            pA1 = *(const half8*)(nbase + nb1[0] + 128);
            pA2 = *(const half8*)(nbase + nb2[0] + 128);
            pA3 = *(const half8*)(nbase + nb3[0] + 128);
            pB0 = *(const half8*)(nbase + nb0[1] + 128);
            pB1 = *(const half8*)(nbase + nb1[1] + 128);
            pB2 = *(const half8*)(nbase + nb2[1] + 128);
            pB3 = *(const half8*)(nbase + nb3[1] + 128);
        }

        // ================= phase 2 (byte-identical to v9) =================
        const _Float16* wr0 = w2t + ((size_t)(wv * 2 + 0) * 16 + c16) * 2048 + ch * 512;
        const _Float16* wr1 = w2t + ((size_t)(wv * 2 + 1) * 16 + c16) * 2048 + ch * 512;
        #pragma unroll 4
        for (int kt = 0; kt < 16; ++kt) {
            const int cb2  = kt * 32 + quad * 8;
            const int mask = (((cb2 >> 6) ^ c16) & 7) << 3;
            half8 t0 = *(const half8*)&s_T[c16 * 512        + (cb2 ^ mask)];
            half8 t1 = *(const half8*)&s_T[(16 + c16) * 512 + (cb2 ^ mask)];
            half8 b0 = *(const half8*)(wr0 + cb2);
            half8 b1 = *(const half8*)(wr1 + cb2);
            a00 = __builtin_amdgcn_mfma_f32_16x16x32_f16(t0, b0, a00, 0, 0, 0);
            a10 = __builtin_amdgcn_mfma_f32_16x16x32_f16(t1, b0, a10, 0, 0, 0);
            a01 = __builtin_amdgcn_mfma_f32_16x16x32_f16(t0, b1, a01, 0, 0, 0);
            a11 = __builtin_amdgcn_mfma_f32_16x16x32_f16(t1, b1, a11, 0, 0, 0);
        }
        __syncthreads();   // before next chunk's phase 1 overwrites s_T
    }

    // ---- epilogue: stage through s_T (dead) -> one contiguous 16KB block write ----
    float* sf = (float*)s_T;
    const float sc = 1.0f / (float)NK;
    const int mb = (wv << 5) + c16;
    #pragma unroll
    for (int g = 0; g < 4; ++g) {
        const int r0 = quad * 4 + g;
        sf[r0 * NF + mb]             = a00[g] * sc;
        sf[r0 * NF + mb + 16]        = a01[g] * sc;
        sf[(r0 + 16) * NF + mb]      = a10[g] * sc;
        sf[(r0 + 16) * NF + mb + 16] = a11[g] * sc;
    }
    __syncthreads();
    const int lim = (N - row0) * NF;             // floats valid (last block: 16 rows)
    float* ob = out + (size_t)row0 * NF;
    #pragma unroll
    for (int u = 0; u < 4; ++u) {
        const int idx = (tid + u * 256) * 4;
        if (idx < lim) *(float4v*)&ob[idx] = *(const float4v*)&sf[idx];
    }
}

extern "C" void kernel_launch(void* const* d_in, const int* in_sizes, int n_in,
                              void* d_out, int out_size, void* d_ws, size_t ws_size,
                              hipStream_t stream) {
    const float* nodes = (const float*)d_in[0];
    const int*   nlist = (const int*)d_in[1];
    const float* edges = (const float*)d_in[2];
    const float* w     = (const float*)d_in[3];
    float* out = (float*)d_out;

    const int N = in_sizes[0] / NF;   // 50000

    _Float16* w2t     = (_Float16*)d_ws;                       // 512KB
    _Float16* nodes_h = (_Float16*)((char*)d_ws + 524288);     // 12.8MB

    const int n4 = (N * NF) / 4;
    k_prep_nodes<<<(n4 + 255) / 256, 256, 0, stream>>>(nodes, nodes_h, n4);
    k_prep_w<<<(NF * NF * NE) / 256, 256, 0, stream>>>(w, w2t);

    const int blocks = (N + RPB - 1) / RPB;                    // 1563
    k_mp<<<blocks, 256, 0, stream>>>(nodes_h, nlist, edges, w2t, out, N);
}

// Round 15
// 359.588 us; speedup vs baseline: 1.1493x; 1.1006x over previous
//
#include <hip/hip_runtime.h>

// MPLayer: out[i,m] = (1/K) sum_{j,l,n} edges[i,j,n] * nodes[nlist[i,j],l] * w[l,m,n]
// N=50000, K=32, F=128, E=16. Two-phase MFMA (fp16 in, fp32 acc):
//   phase 1: T[i][c'] (permuted c-order), per 16-wide l-tile one 16x16x32 MFMA
//   phase 2: out = T @ W2t^T / K, with W2t columns stored in the SAME permuted order
// v13 = v11 (HW-VERIFIED correct: 128B pair-gather + 8-piece s_G XOR + hC1 reg
//   carry) with ONE change: __launch_bounds__(256,3) -> __launch_bounds__(256).
//   r13 post-mortem: v11 spilled ~147MB scratch (WRITE 173 vs 26 predicted)
//   DESPITE reporting only 84 VGPR << the ~168 cap -> the min-waves bound's
//   internal arch/accum budget split forced the spill, not true pressure
//   (same signature as v9's 30MB at (256,4)). Dropping the bound frees the
//   allocator (~150 est.); LDS 48KB still governs occupancy at 3 blocks/CU.
//   NOTE: v12 (LDS re-read variant) was WITHDRAWN before execution — audit
//   found gbuf is overwritten per r, so its odd-chunk re-read would use r=7's
//   data for all rows. The hC1 register carry is the correct mechanism.
//   Everything below the launch bound is byte-identical to v11.

typedef _Float16 half8  __attribute__((ext_vector_type(8)));
typedef _Float16 half4v __attribute__((ext_vector_type(4)));
typedef float    float4v __attribute__((ext_vector_type(4)));
typedef int      int4v  __attribute__((ext_vector_type(4)));
typedef unsigned int uint;

#define NF 128
#define NK 32
#define NE 16
#define RPB 32

__global__ __launch_bounds__(256) void k_prep_nodes(const float* __restrict__ src,
                                                    _Float16* __restrict__ dst, int n4) {
    int i = blockIdx.x * 256 + threadIdx.x;
    if (i < n4) {
        float4v v = ((const float4v*)src)[i];
        half4v h;
        h[0] = (_Float16)v[0]; h[1] = (_Float16)v[1];
        h[2] = (_Float16)v[2]; h[3] = (_Float16)v[3];
        ((half4v*)dst)[i] = h;
    }
}

// W2t permuted: storage index o = m*2048 + ch*512 + ltq*64 + n*4 + g
// corresponds to w[l, m, n] with l = ch*32 + (ltq>>2)*16 + (ltq&3)*4 + g.
__global__ __launch_bounds__(256) void k_prep_w(const float* __restrict__ w,
                                                _Float16* __restrict__ w2t) {
    int o  = blockIdx.x * 256 + threadIdx.x;   // 262144 total, exact grid
    int m  = o >> 11;
    int cf = o & 2047;
    int ch = cf >> 9;
    int cp = cf & 511;
    int ltq = cp >> 6;
    int n   = (cp >> 2) & 15;
    int g   = cp & 3;
    int l = ch * 32 + (ltq >> 2) * 16 + (ltq & 3) * 4 + g;
    w2t[o] = (_Float16)w[(l * NF + m) * NE + n];
}

// MFMA 16x16x32 f16 layouts (verified v1/v2/v6/v9/v11):
//   A: lane holds A[m = lane&15][k = (lane>>4)*8 + jj]
//   B: lane holds B[k = (lane>>4)*8 + jj][n = lane&15]
//   C/D: lane holds D[row = (lane>>4)*4 + g][col = lane&15]
// s_G (per wave, 32 rows x 64 halves = 4KB, one full 128B line per row, covers
//   a chunk PAIR), 8-piece XOR layout — HW-verified by v11:
//   store: row q*8+jl8, piece p8 -> half off (q*8+jl8)*64 + ((p8^q)<<3)
//   read:  piece = c*4 + lt*2 + (c16>>3),
//          addr  = (quad*8+jj)*64 + ((piece^quad)<<3) + (c16&7)
__global__ __launch_bounds__(256) void k_mp(const _Float16* __restrict__ nodes_h,
                                            const int* __restrict__ nlist,
                                            const float* __restrict__ edges,
                                            const _Float16* __restrict__ w2t,
                                            float* __restrict__ out, int N) {
    __shared__ __align__(16) _Float16 s_T[RPB * 512];     // 32 KB
    __shared__ __align__(16) _Float16 s_G[4 * NK * 64];   // 16 KB

    const int tid  = threadIdx.x;
    const int wv   = tid >> 6;
    const int ln   = tid & 63;
    const int quad = ln >> 4;
    const int c16  = ln & 15;
    const int row0 = blockIdx.x * RPB;

    _Float16* __restrict__ gbuf = &s_G[wv * (NK * 64)];
    const float4v zf = {0.f, 0.f, 0.f, 0.f};

    // ---- edge B-fragments (persistent across chunks) ----
    half8 fe[8];
    #pragma unroll
    for (int r = 0; r < 8; ++r) {
        int rg = row0 + wv * 8 + r; if (rg > N - 1) rg = N - 1;
        const float* ep = edges + (size_t)rg * (NK * NE) + quad * (8 * NE) + c16;
        #pragma unroll
        for (int jj = 0; jj < 8; ++jj) fe[r][jj] = (_Float16)ep[jj * NE];
    }

    // ---- gather lanes: jl8 = ln>>3 (row within octet), p8 = ln&7 (16B piece);
    //      load q covers row q*8+jl8 -> one wave instr = 8 rows x 128B full lines
    const int jl8 = ln >> 3;
    const int p8  = ln & 7;
    int nb0[8], nb1[8], nb2[8], nb3[8];
    #pragma unroll
    for (int r = 0; r < 8; ++r) {
        int rg = row0 + wv * 8 + r; if (rg > N - 1) rg = N - 1;
        const int* np = nlist + rg * NK + jl8;
        nb0[r] = np[0]  << 8;        // *256 bytes per fp16 node row
        nb1[r] = np[8]  << 8;
        nb2[r] = np[16] << 8;
        nb3[r] = np[24] << 8;
    }
    const char* nbase = (const char*)nodes_h + (p8 << 4);

    // staging dest offsets (halves): row q*8+jl8, physical piece-slot p8^q
    const int wo0 = (0 * 8 + jl8) * 64 + ((p8 ^ 0) << 3);
    const int wo1 = (1 * 8 + jl8) * 64 + ((p8 ^ 1) << 3);
    const int wo2 = (2 * 8 + jl8) * 64 + ((p8 ^ 2) << 3);
    const int wo3 = (3 * 8 + jl8) * 64 + ((p8 ^ 3) << 3);

    float4v a00 = zf, a01 = zf, a10 = zf, a11 = zf;
    half4v  hC1[8][2];               // odd-chunk T contributions (static idx only)

    // ---- depth-2 prefetch: pA = even r set, pB = odd r set (4 x half8 each) ----
    half8 pA0 = *(const half8*)(nbase + nb0[0]);
    half8 pA1 = *(const half8*)(nbase + nb1[0]);
    half8 pA2 = *(const half8*)(nbase + nb2[0]);
    half8 pA3 = *(const half8*)(nbase + nb3[0]);
    half8 pB0 = *(const half8*)(nbase + nb0[1]);
    half8 pB1 = *(const half8*)(nbase + nb1[1]);
    half8 pB2 = *(const half8*)(nbase + nb2[1]);
    half8 pB3 = *(const half8*)(nbase + nb3[1]);

    for (int ch = 0; ch < 4; ++ch) {
        if ((ch & 1) == 0) {
            // ============ even chunk: gather pair-line + MFMA both halves ============
            const int chb = (ch >> 1) << 7;       // 128B per gather pair
            #pragma unroll
            for (int r = 0; r < 8; ++r) {
                const int il = wv * 8 + r;
                // consume this r's 4-line set; refill the slot for r+2
                if ((r & 1) == 0) {
                    *(half8*)&gbuf[wo0] = pA0;  *(half8*)&gbuf[wo1] = pA1;
                    *(half8*)&gbuf[wo2] = pA2;  *(half8*)&gbuf[wo3] = pA3;
                    if (r < 6) {
                        pA0 = *(const half8*)(nbase + nb0[r + 2] + chb);
                        pA1 = *(const half8*)(nbase + nb1[r + 2] + chb);
                        pA2 = *(const half8*)(nbase + nb2[r + 2] + chb);
                        pA3 = *(const half8*)(nbase + nb3[r + 2] + chb);
                    }
                } else {
                    *(half8*)&gbuf[wo0] = pB0;  *(half8*)&gbuf[wo1] = pB1;
                    *(half8*)&gbuf[wo2] = pB2;  *(half8*)&gbuf[wo3] = pB3;
                    if (r < 6) {
                        pB0 = *(const half8*)(nbase + nb0[r + 2] + chb);
                        pB1 = *(const half8*)(nbase + nb1[r + 2] + chb);
                        pB2 = *(const half8*)(nbase + nb2[r + 2] + chb);
                        pB3 = *(const half8*)(nbase + nb3[r + 2] + chb);
                    }
                }
                // per-wave buffer, in-order LDS: no barrier needed.
                // c = 0 (this chunk) and c = 1 (next chunk, held in regs)
                #pragma unroll
                for (int c = 0; c < 2; ++c) {
                    #pragma unroll
                    for (int lt = 0; lt < 2; ++lt) {
                        const int piece = c * 4 + lt * 2 + (c16 >> 3);
                        const int rbase = quad * 512 + ((piece ^ quad) << 3) + (c16 & 7);
                        uint t0 = *(const unsigned short*)&gbuf[rbase + 0 * 64];
                        uint t1 = *(const unsigned short*)&gbuf[rbase + 1 * 64];
                        uint t2 = *(const unsigned short*)&gbuf[rbase + 2 * 64];
                        uint t3 = *(const unsigned short*)&gbuf[rbase + 3 * 64];
                        uint t4 = *(const unsigned short*)&gbuf[rbase + 4 * 64];
                        uint t5 = *(const unsigned short*)&gbuf[rbase + 5 * 64];
                        uint t6 = *(const unsigned short*)&gbuf[rbase + 6 * 64];
                        uint t7 = *(const unsigned short*)&gbuf[rbase + 7 * 64];
                        int4v pv;
                        pv[0] = (int)(t0 | (t1 << 16));
                        pv[1] = (int)(t2 | (t3 << 16));
                        pv[2] = (int)(t4 | (t5 << 16));
                        pv[3] = (int)(t6 | (t7 << 16));
                        half8 av = __builtin_bit_cast(half8, pv);
                        float4v d = __builtin_amdgcn_mfma_f32_16x16x32_f16(av, fe[r], zf, 0, 0, 0);
                        half4v hv;
                        hv[0] = (_Float16)d[0]; hv[1] = (_Float16)d[1];
                        hv[2] = (_Float16)d[2]; hv[3] = (_Float16)d[3];
                        if (c == 0) {
                            // T store: c' = ltq*64 + c16*4 + g, XOR-swizzled by i-row
                            const int ltq  = lt * 4 + quad;
                            const int cb   = ltq * 64 + c16 * 4;
                            const int phys = cb ^ (((ltq ^ il) & 7) << 3);
                            *(half4v*)&s_T[il * 512 + phys] = hv;
                        } else {
                            hC1[r][lt] = hv;             // held for chunk ch+1
                        }
                    }
                }
            }
        } else {
            // ============ odd chunk: loadless phase 1 — dump held regs ============
            #pragma unroll
            for (int r = 0; r < 8; ++r) {
                const int il = wv * 8 + r;
                #pragma unroll
                for (int lt = 0; lt < 2; ++lt) {
                    const int ltq  = lt * 4 + quad;
                    const int cb   = ltq * 64 + c16 * 4;
                    const int phys = cb ^ (((ltq ^ il) & 7) << 3);
                    *(half4v*)&s_T[il * 512 + phys] = hC1[r][lt];
                }
            }
        }
        __syncthreads();

        // ---- at ch==1: prefetch gather-pair g=1's r=0,r=1 sets (8 loads);
        //      they ride over ch1's phase 2 + barrier, land for ch2 ----
        if (ch == 1) {
            pA0 = *(const half8*)(nbase + nb0[0] + 128);
            pA1 = *(const half8*)(nbase + nb1[0] + 128);
            pA2 = *(const half8*)(nbase + nb2[0] + 128);
            pA3 = *(const half8*)(nbase + nb3[0] + 128);
            pB0 = *(const half8*)(nbase + nb0[1] + 128);
            pB1 = *(const half8*)(nbase + nb1[1] + 128);
            pB2 = *(const half8*)(nbase + nb2[1] + 128);
            pB3 = *(const half8*)(nbase + nb3[1] + 128);
        }

        // ================= phase 2 (byte-identical to v9/v11) =================
        const _Float16* wr0 = w2t + ((size_t)(wv * 2 + 0) * 16 + c16) * 2048 + ch * 512;
        const _Float16* wr1 = w2t + ((size_t)(wv * 2 + 1) * 16 + c16) * 2048 + ch * 512;
        #pragma unroll 4
        for (int kt = 0; kt < 16; ++kt) {
            const int cb2  = kt * 32 + quad * 8;
            const int mask = (((cb2 >> 6) ^ c16) & 7) << 3;
            half8 t0 = *(const half8*)&s_T[c16 * 512        + (cb2 ^ mask)];
            half8 t1 = *(const half8*)&s_T[(16 + c16) * 512 + (cb2 ^ mask)];
            half8 b0 = *(const half8*)(wr0 + cb2);
            half8 b1 = *(const half8*)(wr1 + cb2);
            a00 = __builtin_amdgcn_mfma_f32_16x16x32_f16(t0, b0, a00, 0, 0, 0);
            a10 = __builtin_amdgcn_mfma_f32_16x16x32_f16(t1, b0, a10, 0, 0, 0);
            a01 = __builtin_amdgcn_mfma_f32_16x16x32_f16(t0, b1, a01, 0, 0, 0);
            a11 = __builtin_amdgcn_mfma_f32_16x16x32_f16(t1, b1, a11, 0, 0, 0);
        }
        __syncthreads();   // before next chunk's phase 1 overwrites s_T
    }

    // ---- epilogue: stage through s_T (dead) -> one contiguous 16KB block write ----
    float* sf = (float*)s_T;
    const float sc = 1.0f / (float)NK;
    const int mb = (wv << 5) + c16;
    #pragma unroll
    for (int g = 0; g < 4; ++g) {
        const int r0 = quad * 4 + g;
        sf[r0 * NF + mb]             = a00[g] * sc;
        sf[r0 * NF + mb + 16]        = a01[g] * sc;
        sf[(r0 + 16) * NF + mb]      = a10[g] * sc;
        sf[(r0 + 16) * NF + mb + 16] = a11[g] * sc;
    }
    __syncthreads();
    const int lim = (N - row0) * NF;             // floats valid (last block: 16 rows)
    float* ob = out + (size_t)row0 * NF;
    #pragma unroll
    for (int u = 0; u < 4; ++u) {
        const int idx = (tid + u * 256) * 4;
        if (idx < lim) *(float4v*)&ob[idx] = *(const float4v*)&sf[idx];
    }
}

extern "C" void kernel_launch(void* const* d_in, const int* in_sizes, int n_in,
                              void* d_out, int out_size, void* d_ws, size_t ws_size,
                              hipStream_t stream) {
    const float* nodes = (const float*)d_in[0];
    const int*   nlist = (const int*)d_in[1];
    const float* edges = (const float*)d_in[2];
    const float* w     = (const float*)d_in[3];
    float* out = (float*)d_out;

    const int N = in_sizes[0] / NF;   // 50000

    _Float16* w2t     = (_Float16*)d_ws;                       // 512KB
    _Float16* nodes_h = (_Float16*)((char*)d_ws + 524288);     // 12.8MB

    const int n4 = (N * NF) / 4;
    k_prep_nodes<<<(n4 + 255) / 256, 256, 0, stream>>>(nodes, nodes_h, n4);
    k_prep_w<<<(NF * NF * NE) / 256, 256, 0, stream>>>(w, w2t);

    const int blocks = (N + RPB - 1) / RPB;                    // 1563
    k_mp<<<blocks, 256, 0, stream>>>(nodes_h, nlist, edges, w2t, out, N);
}